// Round 3
// baseline (499.037 us; speedup 1.0000x reference)
//
#include <hip/hip_runtime.h>
#include <hip/hip_fp16.h>

using f16x8 = __attribute__((ext_vector_type(8))) _Float16;
using f32x4 = __attribute__((ext_vector_type(4))) float;

#define B_ 32
#define E_ 8
#define O_ 192
#define I_ 192
#define H_ 56
#define W_ 56
#define HW_ 3136
#define IK_ 1728
#define WSZ_ (O_ * IK_)  // 331776 per expert

// Workspace:
//   wT:   [b][s=9][i8=24][o=192][j=8] fp16   (10,616,832 elems)
//   xT:   [b][icb=6][hw=3136][i%32]   fp16   (19,267,584 elems)
//   bmix: [b][192] float
#define WT_E ((size_t)B_ * 9 * 24 * O_ * 8)
#define XT_E ((size_t)B_ * 6 * HW_ * 32)
#define S_STRIDE 36864   // 24*192*8, halves
#define ICB_STRIDE 100352  // HW_*32, halves

// ---------------------------------------------------------------------------
// Mix: one thread per (b,o,i). Reads Wt contiguously (9 floats per e),
// writes 9 fp16 (scattered 2B, L2-combined). Also bias dot for i==0.
// Grid: 32*192*192/256 = 4608 blocks -> 18432 waves (72/CU).
// ---------------------------------------------------------------------------
__global__ __launch_bounds__(256) void mix_w(
    const float* __restrict__ r, const float* __restrict__ Wt,
    const float* __restrict__ bias, _Float16* __restrict__ wT,
    float* __restrict__ bmix) {
    int gid = blockIdx.x * 256 + threadIdx.x;
    int b = gid / (O_ * I_);
    int rem = gid - b * (O_ * I_);
    int o = rem / I_;
    int i = rem - o * I_;

    float rb[E_];
#pragma unroll
    for (int e = 0; e < E_; ++e) rb[e] = r[b * E_ + e];

    float acc[9];
#pragma unroll
    for (int s = 0; s < 9; ++s) acc[s] = 0.f;
#pragma unroll
    for (int e = 0; e < E_; ++e) {
        const float* wp = Wt + (size_t)e * WSZ_ + (size_t)rem * 9;
#pragma unroll
        for (int s = 0; s < 9; ++s) acc[s] = fmaf(rb[e], wp[s], acc[s]);
    }
    size_t base =
        (((size_t)(b * 9) * 24 + (i >> 3)) * O_ + o) * 8 + (i & 7);
#pragma unroll
    for (int s = 0; s < 9; ++s)
        wT[base + (size_t)s * S_STRIDE] = (_Float16)acc[s];

    if (i == 0) {
        float bacc = 0.f;
#pragma unroll
        for (int e = 0; e < E_; ++e)
            bacc = fmaf(rb[e], bias[e * O_ + o], bacc);
        bmix[b * O_ + o] = bacc;
    }
}

// ---------------------------------------------------------------------------
// x: [b][i][hw] fp32 -> xT [b][i/32][hw][i%32] fp16 via LDS 64x64 transpose.
// ---------------------------------------------------------------------------
__global__ __launch_bounds__(256) void xsplit(const float* __restrict__ x,
                                              _Float16* __restrict__ xT) {
    __shared__ float tile[64][65];
    int t = threadIdx.x, tx = t & 63, ty = t >> 6;
    int b = blockIdx.z, i0 = blockIdx.y * 64, hw0 = blockIdx.x * 64;
    const float* xb = x + ((size_t)b * I_ + i0) * HW_ + hw0;
#pragma unroll
    for (int k = 0; k < 16; ++k) {
        int il = ty * 16 + k;
        tile[il][tx] = xb[(size_t)il * HW_ + tx];
    }
    __syncthreads();
    int i = i0 + tx;
#pragma unroll
    for (int k = 0; k < 16; ++k) {
        int hwl = ty * 16 + k;
        xT[(((size_t)b * 6 + (i >> 5)) * HW_ + hw0 + hwl) * 32 + (i & 31)] =
            (_Float16)tile[tx][hwl];
    }
}

// ---------------------------------------------------------------------------
// Conv: 256 thr = 4 waves (2 o x 2 p). Block tile 96 o x 224 p (4 h-rows).
// Wave tile 48 o x 112 p: M_rep=3, N_rep=7, 16x16x32 f16 MFMA, K=1728 in 6
// chunks of 32. LDS x tile [6 rows][58 w][32 i] fp16 = 22,272 B, double-
// buffered (44.5 KB -> 3 blocks/CU). Reg-staged async split: issue loads for
// chunk k+2 before compute of k+1; one barrier per chunk. 16B chunks XOR-
// swizzled (slot = c ^ ((row>>1)&3)) on both write and read.
// ---------------------------------------------------------------------------
__global__ __launch_bounds__(256, 3) void conv_f16(
    const _Float16* __restrict__ xT, const _Float16* __restrict__ wT,
    const float* __restrict__ bmix, float* __restrict__ out) {
    __shared__ __align__(16) unsigned char xs[2][22272];

    const int t = threadIdx.x;
    const int lane = t & 63, wv = t >> 6;
    const int lc = lane & 15, g = lane >> 4;
    const int h0 = blockIdx.x * 4;
    const int ob = blockIdx.y * 96 + (wv >> 1) * 48;
    const int pbase = (wv & 1) * 112;
    const int b = blockIdx.z;

    int rowbase[7];
#pragma unroll
    for (int f = 0; f < 7; ++f) {
        int ploc = pbase + f * 16 + lc;
        rowbase[f] = (ploc / 56) * 58 + (ploc % 56);
    }

    // Per-thread staging geometry (fixed across chunks).
    int soff[6];   // LDS byte offset, -1 if no chunk for this (q,t)
    int qoff[6];   // global offset in halves (icb=0), -1 if OOB (zero-fill)
#pragma unroll
    for (int q = 0; q < 6; ++q) {
        int idx = q * 256 + t;
        if (idx < 1392) {
            int row = idx >> 2, c = idx & 3;
            int rr = row / 58, ww = row - rr * 58;
            soff[q] = row * 64 + (((c ^ (row >> 1)) & 3) << 4);
            int h = h0 - 1 + rr, w = ww - 1;
            if ((unsigned)h < (unsigned)H_ && (unsigned)w < (unsigned)W_)
                qoff[q] = (((b * 6) * HW_ + h * W_ + w) << 5) + c * 8;
            else
                qoff[q] = -1;
        } else {
            soff[q] = -1;
            qoff[q] = -1;
        }
    }

    f16x8 stg[6];
    const f16x8 zero8 = (f16x8){0, 0, 0, 0, 0, 0, 0, 0};

#define LOADSTAGE(icb)                                                      \
    {                                                                       \
        _Pragma("unroll") for (int q = 0; q < 6; ++q) {                     \
            stg[q] = (qoff[q] >= 0)                                         \
                         ? *(const f16x8*)(xT + qoff[q] +                   \
                                           (icb) * ICB_STRIDE)              \
                         : zero8;                                           \
        }                                                                   \
    }
#define WRITESTAGE(buf)                                                     \
    {                                                                       \
        _Pragma("unroll") for (int q = 0; q < 6; ++q) {                     \
            if (soff[q] >= 0) *(f16x8*)(xs[buf] + soff[q]) = stg[q];        \
        }                                                                   \
    }

    f32x4 acc[3][7];
#pragma unroll
    for (int mi = 0; mi < 3; ++mi)
#pragma unroll
        for (int f = 0; f < 7; ++f) acc[mi][f] = (f32x4){0.f, 0.f, 0.f, 0.f};

    LOADSTAGE(0);
    WRITESTAGE(0);
    LOADSTAGE(1);
    __syncthreads();

    for (int k = 0; k < 6; ++k) {
        const int buf = k & 1;
        // ---- compute chunk k
#pragma unroll
        for (int s = 0; s < 9; ++s) {
            const int dh = s / 3, dw = s - dh * 3;
            f16x8 ah[3];
#pragma unroll
            for (int mi = 0; mi < 3; ++mi)
                ah[mi] = *(const f16x8*)(wT +
                                         ((((size_t)(b * 9 + s) * 24 +
                                            k * 4 + g) *
                                               O_ +
                                           (ob + mi * 16 + lc))
                                          << 3));
#pragma unroll
            for (int f = 0; f < 7; ++f) {
                int row = rowbase[f] + dh * 58 + dw;
                int off = row * 64 + (((g ^ (row >> 1)) & 3) << 4);
                f16x8 bv = *(const f16x8*)(xs[buf] + off);
#pragma unroll
                for (int mi = 0; mi < 3; ++mi)
                    acc[mi][f] = __builtin_amdgcn_mfma_f32_16x16x32_f16(
                        ah[mi], bv, acc[mi][f], 0, 0, 0);
            }
        }
        if (k < 5) {
            WRITESTAGE(buf ^ 1);
            if (k < 4) LOADSTAGE(k + 2);
            __syncthreads();
        }
    }

    // ---- epilogue: D layout col(lane&15)=p, row((lane>>4)*4+j)=o
#pragma unroll
    for (int mi = 0; mi < 3; ++mi) {
#pragma unroll
        for (int j = 0; j < 4; ++j) {
            int o = ob + mi * 16 + g * 4 + j;
            float bs = bmix[b * O_ + o];
            float* op = out + ((size_t)(b * O_ + o)) * HW_ + (size_t)h0 * W_;
#pragma unroll
            for (int f = 0; f < 7; ++f) {
                int ploc = pbase + f * 16 + lc;
                op[ploc] = acc[mi][f][j] + bs;
            }
        }
    }
#undef LOADSTAGE
#undef WRITESTAGE
}

// ---------------------------------------------------------------------------
// fp32 fallback (only if ws_size too small).
// ---------------------------------------------------------------------------
__global__ __launch_bounds__(256, 2) void condconv_fp32(
    const float* __restrict__ x, const float* __restrict__ wsrc,
    const float* __restrict__ r, const float* __restrict__ bias,
    float* __restrict__ out) {
    __shared__ float xsf[16][6][58];
    __shared__ float wsm[16 * 9][68];
    const int t = threadIdx.x;
    const int wg = t & 7, hg = (t >> 3) & 1, og = t >> 4;
    const int h0 = blockIdx.x * 4, o0 = blockIdx.y * 64, b = blockIdx.z;
    const float* xb = x + (size_t)b * I_ * H_ * W_;
    float rb[E_];
#pragma unroll
    for (int e = 0; e < E_; ++e) rb[e] = r[b * E_ + e];
    float acc[4][2][7];
#pragma unroll
    for (int oo = 0; oo < 4; ++oo)
#pragma unroll
        for (int hh = 0; hh < 2; ++hh)
#pragma unroll
            for (int ww = 0; ww < 7; ++ww) acc[oo][hh][ww] = 0.f;
    for (int ic = 0; ic < I_; ic += 16) {
        __syncthreads();
        for (int idx = t; idx < 16 * 6 * 58; idx += 256) {
            int ch = idx / (6 * 58), rem = idx - ch * (6 * 58);
            int rr = rem / 58, cc = rem - rr * 58;
            int hgl = h0 - 1 + rr, wgl = cc - 1;
            float v = 0.f;
            if ((unsigned)hgl < H_ && (unsigned)wgl < W_)
                v = xb[(size_t)(ic + ch) * (H_ * W_) + hgl * W_ + wgl];
            ((float*)xsf)[idx] = v;
        }
        for (int idx = t; idx < 64 * 144; idx += 256) {
            int o = idx / 144, ikl = idx - o * 144;
            float v = 0.f;
#pragma unroll
            for (int e = 0; e < E_; ++e)
                v = fmaf(rb[e],
                         wsrc[(size_t)e * WSZ_ + (size_t)(o0 + o) * IK_ +
                              ic * 9 + ikl],
                         v);
            wsm[ikl][o] = v;
        }
        __syncthreads();
        for (int i = 0; i < 16; ++i) {
#pragma unroll
            for (int kh = 0; kh < 3; ++kh) {
                float xr[2][9];
#pragma unroll
                for (int hh = 0; hh < 2; ++hh)
#pragma unroll
                    for (int c = 0; c < 9; ++c)
                        xr[hh][c] = xsf[i][hg * 2 + hh + kh][wg * 7 + c];
#pragma unroll
                for (int kw = 0; kw < 3; ++kw) {
                    float4 wv =
                        *(const float4*)&wsm[i * 9 + kh * 3 + kw][og * 4];
                    float wreg[4] = {wv.x, wv.y, wv.z, wv.w};
#pragma unroll
                    for (int oo = 0; oo < 4; ++oo)
#pragma unroll
                        for (int hh = 0; hh < 2; ++hh)
#pragma unroll
                            for (int ww = 0; ww < 7; ++ww)
                                acc[oo][hh][ww] =
                                    fmaf(wreg[oo], xr[hh][kw + ww],
                                         acc[oo][hh][ww]);
                }
            }
        }
    }
#pragma unroll
    for (int oo = 0; oo < 4; ++oo) {
        int o = o0 + og * 4 + oo;
        float bs = 0.f;
#pragma unroll
        for (int e = 0; e < E_; ++e) bs = fmaf(rb[e], bias[e * O_ + o], bs);
        float* ob = out + ((size_t)b * O_ + o) * (H_ * W_);
#pragma unroll
        for (int hh = 0; hh < 2; ++hh) {
            int h = h0 + hg * 2 + hh;
#pragma unroll
            for (int ww = 0; ww < 7; ++ww)
                ob[h * W_ + wg * 7 + ww] = acc[oo][hh][ww] + bs;
        }
    }
}

extern "C" void kernel_launch(void* const* d_in, const int* in_sizes, int n_in,
                              void* d_out, int out_size, void* d_ws,
                              size_t ws_size, hipStream_t stream) {
    const float* x = (const float*)d_in[0];
    const float* r = (const float*)d_in[1];
    const float* Wt = (const float*)d_in[2];
    const float* bias = (const float*)d_in[3];
    float* out = (float*)d_out;

    const size_t need = WT_E * 2 + XT_E * 2 + (size_t)B_ * O_ * 4;

    if (ws_size >= need) {
        unsigned char* p = (unsigned char*)d_ws;
        _Float16* wT = (_Float16*)p;
        p += WT_E * 2;
        _Float16* xT = (_Float16*)p;
        p += XT_E * 2;
        float* bmix = (float*)p;

        mix_w<<<(B_ * O_ * I_) / 256, 256, 0, stream>>>(r, Wt, bias, wT, bmix);
        xsplit<<<dim3(HW_ / 64, I_ / 64, B_), 256, 0, stream>>>(x, xT);
        conv_f16<<<dim3(H_ / 4, 2, B_), 256, 0, stream>>>(xT, wT, bmix, out);
    } else {
        condconv_fp32<<<dim3(H_ / 4, O_ / 64, B_), 256, 0, stream>>>(x, Wt, r,
                                                                     bias, out);
    }
}

// Round 5
// 446.730 us; speedup vs baseline: 1.1171x; 1.1171x over previous
//
#include <hip/hip_runtime.h>
#include <hip/hip_fp16.h>

using f16x8 = __attribute__((ext_vector_type(8))) _Float16;
using f32x4 = __attribute__((ext_vector_type(4))) float;

#define B_ 32
#define E_ 8
#define O_ 192
#define I_ 192
#define H_ 56
#define W_ 56
#define HW_ 3136
#define IK_ 1728
#define WSZ_ (O_ * IK_)  // 331776 per expert

// Workspace:
//   wT:   [b][s=9][i8=24][o=192][j=8] fp16   (10,616,832 elems)
//   xT:   [b][icb=6][hw=3136][i%32]   fp16   (19,267,584 elems)
//   bmix: [b][192] float
#define WT_E ((size_t)B_ * 9 * 24 * O_ * 8)
#define XT_E ((size_t)B_ * 6 * HW_ * 32)
#define ICB_STRIDE (HW_ * 32)  // halves

// ---------------------------------------------------------------------------
// Mix, W-stationary: block = (s, i8), 192 threads (t = o). Each thread holds
// we[e][j] (64 floats) in registers, loops all 32 b, emits one 16 B store
// per b at wT[b][s][i8][o][0..8). Wt read exactly once total. Block 0 also
// computes bmix.
// ---------------------------------------------------------------------------
__global__ __launch_bounds__(192) void mix_w(
    const float* __restrict__ r, const float* __restrict__ Wt,
    const float* __restrict__ bias, _Float16* __restrict__ wT,
    float* __restrict__ bmix) {
    const int t = threadIdx.x;               // o
    const int s = blockIdx.x % 9;
    const int i8 = blockIdx.x / 9;           // 0..23

    float we[64];
#pragma unroll
    for (int e = 0; e < E_; ++e)
#pragma unroll
        for (int j = 0; j < 8; ++j)
            we[e * 8 + j] =
                Wt[(size_t)e * WSZ_ + (size_t)t * IK_ + (i8 * 8 + j) * 9 + s];

    for (int b = 0; b < B_; ++b) {
        float acc[8];
#pragma unroll
        for (int j = 0; j < 8; ++j) acc[j] = 0.f;
#pragma unroll
        for (int e = 0; e < E_; ++e) {
            float rv = r[b * E_ + e];
#pragma unroll
            for (int j = 0; j < 8; ++j)
                acc[j] = fmaf(rv, we[e * 8 + j], acc[j]);
        }
        f16x8 v;
#pragma unroll
        for (int j = 0; j < 8; ++j) v[j] = (_Float16)acc[j];
        *(f16x8*)(wT + ((((size_t)(b * 9 + s)) * 24 + i8) * O_ + t) * 8) = v;
    }

    if (blockIdx.x == 0) {  // bias mix: t = o
        for (int b = 0; b < B_; ++b) {
            float bacc = 0.f;
#pragma unroll
            for (int e = 0; e < E_; ++e)
                bacc = fmaf(r[b * E_ + e], bias[e * O_ + t], bacc);
            bmix[b * O_ + t] = bacc;
        }
    }
}

// ---------------------------------------------------------------------------
// x: [b][i][hw] fp32 -> xT [b][i/32][hw][i%32] fp16 via LDS 64x64 transpose.
// ---------------------------------------------------------------------------
__global__ __launch_bounds__(256) void xsplit(const float* __restrict__ x,
                                              _Float16* __restrict__ xT) {
    __shared__ float tile[64][65];
    int t = threadIdx.x, tx = t & 63, ty = t >> 6;
    int b = blockIdx.z, i0 = blockIdx.y * 64, hw0 = blockIdx.x * 64;
    const float* xb = x + ((size_t)b * I_ + i0) * HW_ + hw0;
#pragma unroll
    for (int k = 0; k < 16; ++k) {
        int il = ty * 16 + k;
        tile[il][tx] = xb[(size_t)il * HW_ + tx];
    }
    __syncthreads();
    int i = i0 + tx;
#pragma unroll
    for (int k = 0; k < 16; ++k) {
        int hwl = ty * 16 + k;
        xT[(((size_t)b * 6 + (i >> 5)) * HW_ + hw0 + hwl) * 32 + (i & 31)] =
            (_Float16)tile[tx][hwl];
    }
}

// ---------------------------------------------------------------------------
// Conv: 256 thr = 4 waves, wave wv owns o-group wv*48 (full 192 o per block).
// Block tile 192 o x 112 p (2 h-rows). Wave: M_rep=3, N_rep=7, 16x16x32 f16.
// Grid 28 h-blocks x 32 b, XCD-swizzled so all blocks of a sample b land on
// XCD (b&7): its L2 holds xT[b] (1.2 MB) + wT[b] (0.66 MB).
// LDS x tile [4 rows][58 w][32 i] fp16 = 14848 B, double-buffered (29.7 KB).
// 16 B chunks XOR-swizzled (slot = c ^ ((row>>1)&3)); reg-staged async split
// (load k+2 before compute k+1, write after barrier); 1 barrier per chunk.
// ---------------------------------------------------------------------------
__global__ __launch_bounds__(256, 3) void conv_f16(
    const _Float16* __restrict__ xT, const _Float16* __restrict__ wT,
    const float* __restrict__ bmix, float* __restrict__ out) {
    __shared__ __align__(16) unsigned char xs[2][14848];

    const int t = threadIdx.x;
    const int lane = t & 63, wv = t >> 6;
    const int lc = lane & 15, g = lane >> 4;

    // XCD swizzle: xcd = b & 7
    const int gsw = blockIdx.x;
    const int xcd = gsw & 7;
    const int rest = gsw >> 3;
    const int hb = rest % 28;
    const int b = (rest / 28) * 8 + xcd;
    const int h0 = hb * 2;
    const int ob = wv * 48;

    int rowbase[7];
#pragma unroll
    for (int f = 0; f < 7; ++f) {
        int ploc = f * 16 + lc;            // 0..111
        rowbase[f] = (ploc / 56) * 58 + (ploc % 56);
    }

    // Staging geometry: 4 rows x 58 w = 232 flat rows x 4 16B-chunks = 928.
    int soff[4];   // LDS byte offset (-1: idle)
    int qoff[4];   // xT offset in halves for icb=0 (-1: zero-fill)
#pragma unroll
    for (int q = 0; q < 4; ++q) {
        int idx = q * 256 + t;
        if (idx < 928) {
            int row = idx >> 2, c = idx & 3;
            int rr = row / 58, ww = row - rr * 58;
            soff[q] = row * 64 + (((c ^ (row >> 1)) & 3) << 4);
            int h = h0 - 1 + rr, w = ww - 1;
            if ((unsigned)h < (unsigned)H_ && (unsigned)w < (unsigned)W_)
                qoff[q] = ((b * 6) * HW_ + h * W_ + w) * 32 + c * 8;
            else
                qoff[q] = -1;
        } else {
            soff[q] = -1;
            qoff[q] = -1;
        }
    }

    f16x8 stg[4];
    const f16x8 zero8 = (f16x8){0, 0, 0, 0, 0, 0, 0, 0};

#define LOADSTAGE(icb)                                                       \
    {                                                                        \
        _Pragma("unroll") for (int q = 0; q < 4; ++q) {                      \
            stg[q] = (qoff[q] >= 0)                                          \
                         ? *(const f16x8*)(xT + qoff[q] +                    \
                                           (icb) * ICB_STRIDE)               \
                         : zero8;                                            \
        }                                                                    \
    }
#define WRITESTAGE(buf)                                                      \
    {                                                                        \
        _Pragma("unroll") for (int q = 0; q < 4; ++q) {                      \
            if (soff[q] >= 0) *(f16x8*)(xs[buf] + soff[q]) = stg[q];         \
        }                                                                    \
    }

    f32x4 acc[3][7];
#pragma unroll
    for (int mi = 0; mi < 3; ++mi)
#pragma unroll
        for (int f = 0; f < 7; ++f) acc[mi][f] = (f32x4){0.f, 0.f, 0.f, 0.f};

    LOADSTAGE(0);
    WRITESTAGE(0);
    LOADSTAGE(1);
    __syncthreads();

    for (int k = 0; k < 6; ++k) {
        const int buf = k & 1;
#pragma unroll
        for (int s = 0; s < 9; ++s) {
            const int dh = s / 3, dw = s - dh * 3;
            f16x8 ah[3];
#pragma unroll
            for (int mi = 0; mi < 3; ++mi)
                ah[mi] = *(const f16x8*)(wT +
                                         ((((size_t)(b * 9 + s)) * 24 +
                                           k * 4 + g) *
                                              O_ +
                                          (ob + mi * 16 + lc)) *
                                             8);
#pragma unroll
            for (int f = 0; f < 7; ++f) {
                int row = rowbase[f] + dh * 58 + dw;
                int off = row * 64 + (((g ^ (row >> 1)) & 3) << 4);
                f16x8 bv = *(const f16x8*)(xs[buf] + off);
#pragma unroll
                for (int mi = 0; mi < 3; ++mi)
                    acc[mi][f] = __builtin_amdgcn_mfma_f32_16x16x32_f16(
                        ah[mi], bv, acc[mi][f], 0, 0, 0);
            }
        }
        if (k < 5) {
            WRITESTAGE(buf ^ 1);
            if (k < 4) LOADSTAGE(k + 2);
            __syncthreads();
        }
    }

    // Epilogue: D layout col(lane&15)=p, row((lane>>4)*4+j)=o.
#pragma unroll
    for (int mi = 0; mi < 3; ++mi) {
#pragma unroll
        for (int j = 0; j < 4; ++j) {
            int o = ob + mi * 16 + g * 4 + j;
            float bs = bmix[b * O_ + o];
            float* op = out + ((size_t)(b * O_ + o)) * HW_ + (size_t)h0 * W_;
#pragma unroll
            for (int f = 0; f < 7; ++f) {
                int ploc = f * 16 + lc;
                op[(ploc / 56) * W_ + (ploc % 56)] = acc[mi][f][j] + bs;
            }
        }
    }
#undef LOADSTAGE
#undef WRITESTAGE
}

// ---------------------------------------------------------------------------
// fp32 fallback (only if ws_size too small).
// ---------------------------------------------------------------------------
__global__ __launch_bounds__(256, 2) void condconv_fp32(
    const float* __restrict__ x, const float* __restrict__ wsrc,
    const float* __restrict__ r, const float* __restrict__ bias,
    float* __restrict__ out) {
    __shared__ float xsf[16][6][58];
    __shared__ float wsm[16 * 9][68];
    const int t = threadIdx.x;
    const int wg = t & 7, hg = (t >> 3) & 1, og = t >> 4;
    const int h0 = blockIdx.x * 4, o0 = blockIdx.y * 64, b = blockIdx.z;
    const float* xb = x + (size_t)b * I_ * H_ * W_;
    float rb[E_];
#pragma unroll
    for (int e = 0; e < E_; ++e) rb[e] = r[b * E_ + e];
    float acc[4][2][7];
#pragma unroll
    for (int oo = 0; oo < 4; ++oo)
#pragma unroll
        for (int hh = 0; hh < 2; ++hh)
#pragma unroll
            for (int ww = 0; ww < 7; ++ww) acc[oo][hh][ww] = 0.f;
    for (int ic = 0; ic < I_; ic += 16) {
        __syncthreads();
        for (int idx = t; idx < 16 * 6 * 58; idx += 256) {
            int ch = idx / (6 * 58), rem = idx - ch * (6 * 58);
            int rr = rem / 58, cc = rem - rr * 58;
            int hgl = h0 - 1 + rr, wgl = cc - 1;
            float v = 0.f;
            if ((unsigned)hgl < H_ && (unsigned)wgl < W_)
                v = xb[(size_t)(ic + ch) * (H_ * W_) + hgl * W_ + wgl];
            ((float*)xsf)[idx] = v;
        }
        for (int idx = t; idx < 64 * 144; idx += 256) {
            int o = idx / 144, ikl = idx - o * 144;
            float v = 0.f;
#pragma unroll
            for (int e = 0; e < E_; ++e)
                v = fmaf(rb[e],
                         wsrc[(size_t)e * WSZ_ + (size_t)(o0 + o) * IK_ +
                              ic * 9 + ikl],
                         v);
            wsm[ikl][o] = v;
        }
        __syncthreads();
        for (int i = 0; i < 16; ++i) {
#pragma unroll
            for (int kh = 0; kh < 3; ++kh) {
                float xr[2][9];
#pragma unroll
                for (int hh = 0; hh < 2; ++hh)
#pragma unroll
                    for (int c = 0; c < 9; ++c)
                        xr[hh][c] = xsf[i][hg * 2 + hh + kh][wg * 7 + c];
#pragma unroll
                for (int kw = 0; kw < 3; ++kw) {
                    float4 wv =
                        *(const float4*)&wsm[i * 9 + kh * 3 + kw][og * 4];
                    float wreg[4] = {wv.x, wv.y, wv.z, wv.w};
#pragma unroll
                    for (int oo = 0; oo < 4; ++oo)
#pragma unroll
                        for (int hh = 0; hh < 2; ++hh)
#pragma unroll
                            for (int ww = 0; ww < 7; ++ww)
                                acc[oo][hh][ww] =
                                    fmaf(wreg[oo], xr[hh][kw + ww],
                                         acc[oo][hh][ww]);
                }
            }
        }
    }
#pragma unroll
    for (int oo = 0; oo < 4; ++oo) {
        int o = o0 + og * 4 + oo;
        float bs = 0.f;
#pragma unroll
        for (int e = 0; e < E_; ++e) bs = fmaf(rb[e], bias[e * O_ + o], bs);
        float* ob = out + ((size_t)b * O_ + o) * (H_ * W_);
#pragma unroll
        for (int hh = 0; hh < 2; ++hh) {
            int h = h0 + hg * 2 + hh;
#pragma unroll
            for (int ww = 0; ww < 7; ++ww)
                ob[h * W_ + wg * 7 + ww] = acc[oo][hh][ww] + bs;
        }
    }
}

extern "C" void kernel_launch(void* const* d_in, const int* in_sizes, int n_in,
                              void* d_out, int out_size, void* d_ws,
                              size_t ws_size, hipStream_t stream) {
    const float* x = (const float*)d_in[0];
    const float* r = (const float*)d_in[1];
    const float* Wt = (const float*)d_in[2];
    const float* bias = (const float*)d_in[3];
    float* out = (float*)d_out;

    const size_t need = WT_E * 2 + XT_E * 2 + (size_t)B_ * O_ * 4;

    if (ws_size >= need) {
        unsigned char* p = (unsigned char*)d_ws;
        _Float16* wT = (_Float16*)p;
        p += WT_E * 2;
        _Float16* xT = (_Float16*)p;
        p += XT_E * 2;
        float* bmix = (float*)p;

        mix_w<<<9 * 24, 192, 0, stream>>>(r, Wt, bias, wT, bmix);
        xsplit<<<dim3(HW_ / 64, I_ / 64, B_), 256, 0, stream>>>(x, xT);
        conv_f16<<<dim3(28 * B_), 256, 0, stream>>>(xT, wT, bmix, out);
    } else {
        condconv_fp32<<<dim3(H_ / 4, O_ / 64, B_), 256, 0, stream>>>(x, Wt, r,
                                                                     bias, out);
    }
}